// Round 12
// baseline (297.421 us; speedup 1.0000x reference)
//
#include <hip/hip_runtime.h>
#include <math.h>

#define B_ 8
#define T_ 4096
#define H_ 1024
#define K_ 128
#define V_ 128
#define OUT_ 1024
#define NPROJ 512
#define M_ (B_*T_)          // 32768
#define CC 32               // chunk length
#define NC 128              // chunks per batch

typedef __attribute__((ext_vector_type(8))) short bf16x8;
typedef __attribute__((ext_vector_type(4))) float f32x4;

__device__ inline unsigned short f2bf(float f){
  union{float f; unsigned int u;} x; x.f = f;
  unsigned int r = x.u + 0x7fff + ((x.u>>16)&1);   // RNE
  return (unsigned short)(r>>16);
}
__device__ inline float bf2f(unsigned short u){
  union{unsigned int i; float f;} x; x.i = ((unsigned int)u)<<16; return x.f;
}

#define GL16(gp, lp) __builtin_amdgcn_global_load_lds(\
  (const __attribute__((address_space(1))) unsigned int*)(gp), \
  (__attribute__((address_space(3))) unsigned int*)(lp), 16, 0, 0)

#define MFMA16(a,b,c) __builtin_amdgcn_mfma_f32_16x16x32_bf16((a),(b),(c),0,0,0)

// ---------------- generic tiled transpose+convert: dst[n][k] = bf16(src[k][n])
__global__ __launch_bounds__(256)
void convT(const float* __restrict__ src, unsigned short* __restrict__ dst,
           int Kd, int N) {
  __shared__ float t[32][33];
  int tx = threadIdx.x & 31, ty = threadIdx.x >> 5;   // ty 0..7
  int n0 = blockIdx.x * 32, k0 = blockIdx.y * 32;
  #pragma unroll
  for (int r=0;r<4;r++){
    int k = ty*4 + r;
    t[k][tx] = src[(long)(k0+k)*N + n0 + tx];
  }
  __syncthreads();
  #pragma unroll
  for (int r=0;r<4;r++){
    int n = ty*4 + r;
    dst[(long)(n0+n)*Kd + k0 + tx] = f2bf(t[tx][n]);
  }
}

// ---------------- proj MFMA GEMM v8: coalesced A + sA-dbuf/sB-single counted pipeline
// BM=128, BN=256, BK=64, 512 thr (8 waves, 2Mx4N). LDS 68KB => 2 blocks/CU.
// Per tile: STB -> STA(next) -> LDA(2-ahead) -> vmcnt(4)+lgkm(0)+bar -> FRAGS+MFMA -> bar.
// vmcnt(4) drains STB (older) and leaves the 4 newest LDA in flight.
__global__ __launch_bounds__(512, 4)
void proj_mfma8(const float* __restrict__ A, const unsigned short* __restrict__ Bt,
                const float* __restrict__ bias,
                unsigned short* __restrict__ qbf, unsigned short* __restrict__ kbf,
                float* __restrict__ gf, unsigned short* __restrict__ vbf) {
  __shared__ unsigned short sA[2][128*72];   // 2 x 18 KB, stride 72
  __shared__ unsigned short sB[256*64];      // 32 KB, swizzled slots
  int tid = threadIdx.x, lane = tid & 63, wid = tid >> 6;
  int wm = wid >> 2, wn = wid & 3;
  int l16 = lane & 15, g8 = (lane >> 4) * 8;
  long row0 = (long)blockIdx.y * 128;
  int col0 = blockIdx.x * 256;

  int arow = tid >> 2, acol0 = (tid & 3) * 4;        // coalesced: lanes 0..3 contiguous
  const float* Ab = A + (row0 + arow) * 1024 + acol0;
  int srowB = lane >> 3;
  int scolB = ((lane & 7) ^ srowB) * 8;

  f32x4 acc[4][4];
  #pragma unroll
  for (int i=0;i<4;i++)
    #pragma unroll
    for (int j=0;j<4;j++) acc[i][j] = (f32x4){0.f,0.f,0.f,0.f};

  float4 rE[4], rO[4];

  #define SFENCE __builtin_amdgcn_sched_barrier(0)
  #define LDA(dst_, k0_) { _Pragma("unroll") \
    for (int j_=0;j_<4;j_++) dst_[j_] = *(const float4*)(Ab + (k0_) + j_*16); }
  #define STA(bi_, src_) { _Pragma("unroll") \
    for (int j_=0;j_<4;j_++){ \
      unsigned short o_[4] = {f2bf(src_[j_].x), f2bf(src_[j_].y), \
                              f2bf(src_[j_].z), f2bf(src_[j_].w)}; \
      *(uint2*)&sA[bi_][arow*72 + acol0 + j_*16] = *(uint2*)o_; \
    } }
  #define STB(k0_) { _Pragma("unroll") \
    for (int i_=0;i_<4;i_++){ \
      int r_ = wid*32 + i_*8; \
      GL16(Bt + (long)(col0 + r_ + srowB)*1024 + (k0_) + scolB, &sB[r_*64]); \
    } }
  #define FRAGS(bi_) { _Pragma("unroll") \
    for (int kk2_=0;kk2_<2;kk2_++){ int kk_ = kk2_*32; \
      _Pragma("unroll") \
      for (int mi_=0;mi_<4;mi_++) \
        af[kk2_][mi_] = *(const bf16x8*)&sA[bi_][(wm*64 + mi_*16 + l16)*72 + kk_ + g8]; \
      _Pragma("unroll") \
      for (int ni_=0;ni_<4;ni_++){ \
        int brow_ = wn*64 + ni_*16 + l16; \
        int slot_ = ((kk_ + g8) >> 3) ^ (brow_ & 7); \
        bf[kk2_][ni_] = *(const bf16x8*)&sB[brow_*64 + slot_*8]; \
      } \
    } }
  #define MFMAS { _Pragma("unroll") \
    for (int kk2_=0;kk2_<2;kk2_++) \
      _Pragma("unroll") \
      for (int mi_=0;mi_<4;mi_++) \
        _Pragma("unroll") \
        for (int ni_=0;ni_<4;ni_++) \
          acc[mi_][ni_] = MFMA16(af[kk2_][mi_], bf[kk2_][ni_], acc[mi_][ni_]); }
  #define BARV4 { asm volatile("s_waitcnt vmcnt(4) lgkmcnt(0)" ::: "memory"); \
    SFENCE; __builtin_amdgcn_s_barrier(); SFENCE; }
  #define BARX  { SFENCE; __builtin_amdgcn_s_barrier(); SFENCE; }

  bf16x8 af[2][4], bf[2][4];

  // prologue: sA[0] <- A(0); rE <- A(1); rO <- A(2)
  LDA(rE, 0);    SFENCE;
  STA(0, rE);    SFENCE;          // compiler waits rE
  LDA(rE, 64);   SFENCE;
  LDA(rO, 128);  SFENCE;

  for (int t2 = 0; t2 < 16; t2 += 2) {
    // even tile t2 (cur=0): rE holds A(t2+1)
    STB(t2*64);              SFENCE;
    STA(1, rE);              SFENCE;   // stage A(t2+1) -> sA[1]
    { int kn = (t2+3 > 15) ? 15 : t2+3; LDA(rE, kn*64); } SFENCE;
    BARV4;
    FRAGS(0); MFMAS;
    BARX;
    // odd tile t2+1 (cur=1): rO holds A(t2+2)
    STB((t2+1)*64);          SFENCE;
    if (t2+1 < 15) { STA(0, rO); SFENCE; }   // stage A(t2+2) -> sA[0]
    { int kn = (t2+4 > 15) ? 15 : t2+4; LDA(rO, kn*64); } SFENCE;
    BARV4;
    FRAGS(1); MFMAS;
    BARX;
  }

  #undef SFENCE
  #undef LDA
  #undef STA
  #undef STB
  #undef FRAGS
  #undef MFMAS
  #undef BARV4
  #undef BARX

  // epilogue: wave's 64-col strip -> segment seg of {q,k,g,v}
  int seg = blockIdx.x*2 + (wn>>1);          // 0..3, wave-uniform
  int cbase = (wn&1)*64;
  #pragma unroll
  for (int mi=0;mi<4;mi++){
    #pragma unroll
    for (int ni=0;ni<4;ni++){
      int c = cbase + ni*16 + l16;           // 0..127 within segment
      float bsv = bias[seg*128 + c];
      #pragma unroll
      for (int r=0;r<4;r++){
        long grow = row0 + wm*64 + mi*16 + (lane>>4)*4 + r;
        float v = acc[mi][ni][r] + bsv;
        long off = grow*128 + c;
        if (seg == 0)      qbf[off] = f2bf(v);
        else if (seg == 1) kbf[off] = f2bf(1.f/(1.f+__expf(-v)));
        else if (seg == 2) gf[off]  = 1.f/(1.f+__expf(-v));
        else               vbf[off] = f2bf(v);
      }
    }
  }
}

// ---------------- prep: per (b,c): G cumprod, q~ (in-place), k~ (in-place), k^T, vT, Gc
__global__ __launch_bounds__(128)
void prep(const float* __restrict__ gf, unsigned short* __restrict__ qbf,
          unsigned short* __restrict__ kbf, const unsigned short* __restrict__ vbf,
          unsigned short* __restrict__ khT, unsigned short* __restrict__ vT,
          float* __restrict__ Gc) {
  int k = threadIdx.x;               // 0..127
  int c = blockIdx.x, b = blockIdx.y;
  long base = ((long)b*T_ + (long)c*CC) * 128;
  float G = 1.f;
  float kt[CC];
  unsigned short vv[CC];
  #pragma unroll
  for (int t=0;t<CC;++t){
    long off = base + (long)t*128 + k;
    float g = gf[off];
    G *= g;
    float q = bf2f(qbf[off]);
    qbf[off] = f2bf(q*G);
    float kk = bf2f(kbf[off]);
    float ktl = kk/G;
    kbf[off] = f2bf(ktl);
    kt[t] = ktl;
    vv[t] = vbf[off];                // lane index doubles as v index
  }
  long cb = (long)b*NC + c;
  Gc[cb*128 + k] = G;
  unsigned short ob[CC];
  #pragma unroll
  for (int s=0;s<CC;++s) ob[s] = f2bf(kt[s]*G);
  long tbase = (cb*128 + k)*CC;
  #pragma unroll
  for (int j=0;j<4;j++) *(uint4*)(khT + tbase + j*8) = *(uint4*)(ob + j*8);
  #pragma unroll
  for (int j=0;j<4;j++) *(uint4*)(vT + tbase + j*8) = *(uint4*)(vv + j*8);
}

// ---------------- chunkstate: Ut[c][v][k] = sum_s V[s][v] * k^[s][k]  (bf16 out)
__global__ __launch_bounds__(256)
void chunkstate(const unsigned short* __restrict__ khT, const unsigned short* __restrict__ vT,
                unsigned short* __restrict__ Ut) {
  __shared__ unsigned short kS[128][36];
  __shared__ unsigned short vS[128][36];
  int tid = threadIdx.x, lane = tid&63, w = tid>>6;
  long cb = (long)blockIdx.y*NC + blockIdx.x;
  const unsigned short* kg = khT + cb*4096;
  const unsigned short* vg = vT  + cb*4096;
  #pragma unroll
  for (int j=0;j<2;j++){
    int idx = tid + j*256;           // 512 x uint4
    int r = idx>>2, s8 = (idx&3)*8;
    *(uint4*)&kS[r][s8] = *(const uint4*)(kg + r*32 + s8);
    *(uint4*)&vS[r][s8] = *(const uint4*)(vg + r*32 + s8);
  }
  __syncthreads();
  int l16 = lane&15, g8 = (lane>>4)*8;
  bf16x8 af[2], bfr[8];
  #pragma unroll
  for (int i=0;i<2;i++) af[i] = *(const bf16x8*)&vS[w*32 + i*16 + l16][g8];
  #pragma unroll
  for (int j=0;j<8;j++) bfr[j] = *(const bf16x8*)&kS[j*16 + l16][g8];
  #pragma unroll
  for (int i=0;i<2;i++){
    #pragma unroll
    for (int j=0;j<8;j++){
      f32x4 acc = (f32x4){0.f,0.f,0.f,0.f};
      acc = MFMA16(af[i], bfr[j], acc);
      int kcol = j*16 + l16;
      #pragma unroll
      for (int r=0;r<4;r++){
        int vrow = w*32 + i*16 + (lane>>4)*4 + r;
        Ut[cb*16384 + vrow*128 + kcol] = f2bf(acc[r]);
      }
    }
  }
}

// ---------------- seqstate two-level scan
// Pass A: per (b, seg of 16 chunks): local state from 0 + per-k G-product.
__global__ __launch_bounds__(256)
void seqstate_a(const float* __restrict__ Gc, const unsigned short* __restrict__ Ut,
                float* __restrict__ segB, float* __restrict__ segG) {
  int idx = blockIdx.x*256 + threadIdx.x;    // 0..4095
  int s = blockIdx.y, b = blockIdx.z;
  int v = idx>>5, k0 = (idx&31)*4;
  float cell[4] = {0.f,0.f,0.f,0.f};
  float gp[4] = {1.f,1.f,1.f,1.f};
  long ub = (long)b*NC*16384 + (long)v*128 + k0;
  long gb = (long)b*NC*128 + k0;
  int c0 = s*16;
  #pragma unroll 4
  for (int c=c0; c<c0+16; ++c){
    uint2 u = *(const uint2*)(Ut + ub + (long)c*16384);
    float4 gc = *(const float4*)(Gc + gb + (long)c*128);
    cell[0] = fmaf(cell[0], gc.x, bf2f((unsigned short)(u.x & 0xffff)));
    cell[1] = fmaf(cell[1], gc.y, bf2f((unsigned short)(u.x >> 16)));
    cell[2] = fmaf(cell[2], gc.z, bf2f((unsigned short)(u.y & 0xffff)));
    cell[3] = fmaf(cell[3], gc.w, bf2f((unsigned short)(u.y >> 16)));
    gp[0] *= gc.x; gp[1] *= gc.y; gp[2] *= gc.z; gp[3] *= gc.w;
  }
  long sb = ((long)b*8 + s)*16384 + (long)v*128 + k0;
  *(float4*)(segB + sb) = make_float4(cell[0],cell[1],cell[2],cell[3]);
  if (v == 0)
    *(float4*)(segG + ((long)b*8 + s)*128 + k0) = make_float4(gp[0],gp[1],gp[2],gp[3]);
}

// Pass B: fold upstream segments (<=7 L2-hot loads) -> incoming; re-walk own
// segment writing cellT (in-place over Ut) and fstate at s==7.
__global__ __launch_bounds__(256)
void seqstate_b(const float* __restrict__ Gc, unsigned short* __restrict__ Ut,
                const float* __restrict__ segB, const float* __restrict__ segG,
                float* __restrict__ fstate) {
  int idx = blockIdx.x*256 + threadIdx.x;    // 0..4095
  int s = blockIdx.y, b = blockIdx.z;
  int v = idx>>5, k0 = (idx&31)*4;
  float cell[4] = {0.f,0.f,0.f,0.f};
  for (int sp=0; sp<s; ++sp){                 // uniform bound per block
    float4 bg = *(const float4*)(segG + ((long)b*8 + sp)*128 + k0);
    float4 bb = *(const float4*)(segB + ((long)b*8 + sp)*16384 + (long)v*128 + k0);
    cell[0] = fmaf(cell[0], bg.x, bb.x);
    cell[1] = fmaf(cell[1], bg.y, bb.y);
    cell[2] = fmaf(cell[2], bg.z, bb.z);
    cell[3] = fmaf(cell[3], bg.w, bb.w);
  }
  long ub = (long)b*NC*16384 + (long)v*128 + k0;
  long gb = (long)b*NC*128 + k0;
  int c0 = s*16;
  #pragma unroll 4
  for (int c=c0; c<c0+16; ++c){
    uint2 u = *(const uint2*)(Ut + ub + (long)c*16384);
    float4 gc = *(const float4*)(Gc + gb + (long)c*128);
    unsigned short cb4[4] = {f2bf(cell[0]), f2bf(cell[1]), f2bf(cell[2]), f2bf(cell[3])};
    *(uint2*)(Ut + ub + (long)c*16384) = *(uint2*)cb4;   // cellT[c] (pre-update)
    cell[0] = fmaf(cell[0], gc.x, bf2f((unsigned short)(u.x & 0xffff)));
    cell[1] = fmaf(cell[1], gc.y, bf2f((unsigned short)(u.x >> 16)));
    cell[2] = fmaf(cell[2], gc.z, bf2f((unsigned short)(u.y & 0xffff)));
    cell[3] = fmaf(cell[3], gc.w, bf2f((unsigned short)(u.y >> 16)));
  }
  if (s == 7){
    #pragma unroll
    for (int j=0;j<4;j++)
      fstate[((long)b*128 + k0 + j)*128 + v] = cell[j];
  }
}

// ---------------- chunkout: O = tril(Q~ K~^T) @ V + Q~ @ cellT^T  -> obf bf16
#define CP 140
__global__ __launch_bounds__(256)
void chunkout(const unsigned short* __restrict__ qbf, const unsigned short* __restrict__ kbf,
              const unsigned short* __restrict__ vT, const unsigned short* __restrict__ cellT,
              unsigned short* __restrict__ obf) {
  __shared__ unsigned short qS[32][CP];
  __shared__ unsigned short kS[32][CP];
  __shared__ unsigned short cS[128][CP];
  __shared__ unsigned short vS[128][36];
  __shared__ unsigned short pS[4][32][36];
  int tid = threadIdx.x, lane = tid&63, w = tid>>6;
  long cb = (long)blockIdx.y*NC + blockIdx.x;
  const unsigned short* qg = qbf + cb*4096;
  const unsigned short* kg = kbf + cb*4096;
  const unsigned short* vg = vT  + cb*4096;
  const unsigned short* cg = cellT + cb*16384;
  // stage q,k (32x128), v (128x32), cell (128x128)
  #pragma unroll
  for (int j=0;j<2;j++){
    int idx = tid + j*256;           // 512
    int r = idx>>4, c8 = (idx&15)*8;
    *(uint4*)&qS[r][c8] = *(const uint4*)(qg + r*128 + c8);
    *(uint4*)&kS[r][c8] = *(const uint4*)(kg + r*128 + c8);
    int rv = idx>>2, s8 = (idx&3)*8;
    *(uint4*)&vS[rv][s8] = *(const uint4*)(vg + rv*32 + s8);
  }
  #pragma unroll
  for (int j=0;j<8;j++){
    int idx = tid + j*256;           // 2048
    int r = idx>>4, c8 = (idx&15)*8;
    *(uint4*)&cS[r][c8] = *(const uint4*)(cg + r*128 + c8);
  }
  __syncthreads();

  int l16 = lane&15, g = lane>>4, g8 = g*8;
  // S tiles: S2[s][t], compute (s0,t0),(s0,t1),(s1,t1)
  f32x4 s00 = (f32x4){0.f,0.f,0.f,0.f}, s01 = s00, s11 = s00;
  #pragma unroll
  for (int ks=0; ks<4; ++ks){
    bf16x8 ka = *(const bf16x8*)&kS[l16][ks*32+g8];
    bf16x8 kb = *(const bf16x8*)&kS[16+l16][ks*32+g8];
    bf16x8 qa = *(const bf16x8*)&qS[l16][ks*32+g8];
    bf16x8 qb = *(const bf16x8*)&qS[16+l16][ks*32+g8];
    s00 = MFMA16(ka, qa, s00);
    s01 = MFMA16(ka, qb, s01);
    s11 = MFMA16(kb, qb, s11);
  }
  // P[t][s] = masked S2, bf16. zero quadrant t<16, s>=16
  pS[w][l16][16 + 4*g + (0)] = 0; pS[w][l16][16 + 4*g + 1] = 0;
  pS[w][l16][16 + 4*g + 2] = 0;   pS[w][l16][16 + 4*g + 3] = 0;
  #pragma unroll
  for (int r=0;r<4;r++){
    int sl = 4*g + r;
    pS[w][l16][sl]       = (l16 >= sl) ? f2bf(s00[r]) : (unsigned short)0;
    pS[w][16+l16][sl]    = f2bf(s01[r]);
    pS[w][16+l16][16+sl] = (l16 >= sl) ? f2bf(s11[r]) : (unsigned short)0;
  }
  // O = P@V + Q~@cellT
  f32x4 o[2][2];
  #pragma unroll
  for (int i=0;i<2;i++)
    #pragma unroll
    for (int j=0;j<2;j++) o[i][j] = (f32x4){0.f,0.f,0.f,0.f};
  {
    bf16x8 p0 = *(const bf16x8*)&pS[w][l16][g8];
    bf16x8 p1 = *(const bf16x8*)&pS[w][16+l16][g8];
    bf16x8 v0 = *(const bf16x8*)&vS[w*32 + l16][g8];
    bf16x8 v1 = *(const bf16x8*)&vS[w*32 + 16 + l16][g8];
    o[0][0] = MFMA16(p0, v0, o[0][0]);
    o[0][1] = MFMA16(p0, v1, o[0][1]);
    o[1][0] = MFMA16(p1, v0, o[1][0]);
    o[1][1] = MFMA16(p1, v1, o[1][1]);
  }
  #pragma unroll
  for (int ks=0; ks<4; ++ks){
    bf16x8 qa = *(const bf16x8*)&qS[l16][ks*32+g8];
    bf16x8 qb = *(const bf16x8*)&qS[16+l16][ks*32+g8];
    bf16x8 c0 = *(const bf16x8*)&cS[w*32 + l16][ks*32+g8];
    bf16x8 c1 = *(const bf16x8*)&cS[w*32 + 16 + l16][ks*32+g8];
    o[0][0] = MFMA16(qa, c0, o[0][0]);
    o[0][1] = MFMA16(qa, c1, o[0][1]);
    o[1][0] = MFMA16(qb, c0, o[1][0]);
    o[1][1] = MFMA16(qb, c1, o[1][1]);
  }
  // store obf[t][v]
  #pragma unroll
  for (int ti=0;ti<2;ti++)
    #pragma unroll
    for (int vi=0;vi<2;vi++)
      #pragma unroll
      for (int r=0;r<4;r++){
        int t = ti*16 + 4*g + r;
        int v = w*32 + vi*16 + l16;
        obf[cb*4096 + (long)t*128 + v] = f2bf(o[ti][vi][r]);
      }
}

// ---------------- out MFMA GEMM: [32768x128]bf16 @ [128x1024] + bias -> f32
__global__ __launch_bounds__(256)
void out_mfma(const unsigned short* __restrict__ A, const unsigned short* __restrict__ Bt,
              const float* __restrict__ bias, float* __restrict__ C) {
  __shared__ unsigned short As[128*32];
  __shared__ unsigned short Bs[128*32];
  int tid = threadIdx.x, lane = tid & 63, wid = tid >> 6;
  long row0 = (long)blockIdx.y * 128;
  int col0 = blockIdx.x * 128;
  f32x4 acc[4][4];
  #pragma unroll
  for (int i=0;i<4;i++)
    #pragma unroll
    for (int j=0;j<4;j++) acc[i][j] = (f32x4){0.f,0.f,0.f,0.f};

  const unsigned short* Ab = A + row0*128;
  const unsigned short* Bb = Bt + (long)col0*128;
  int srow = lane >> 2;
  int soff = (lane & 3) * 8;
  int wrow = (wid>>1)*64, wcol = (wid&1)*64;

  for (int k0 = 0; k0 < 128; k0 += 32) {
    #pragma unroll
    for (int i=0;i<2;i++){
      int r = wid*32 + i*16;
      GL16(Ab + (long)(r + srow)*128 + k0 + soff, &As[r*32]);
      GL16(Bb + (long)(r + srow)*128 + k0 + soff, &Bs[r*32]);
    }
    __syncthreads();
    bf16x8 af[4], bfr[4];
    #pragma unroll
    for (int mi=0;mi<4;mi++)
      af[mi] = *(const bf16x8*)&As[(wrow + mi*16 + (lane&15))*32 + (lane>>4)*8];
    #pragma unroll
    for (int ni=0;ni<4;ni++)
      bfr[ni] = *(const bf16x8*)&Bs[(wcol + ni*16 + (lane&15))*32 + (lane>>4)*8];
    #pragma unroll
    for (int mi=0;mi<4;mi++)
      #pragma unroll
      for (int ni=0;ni<4;ni++)
        acc[mi][ni] = MFMA16(af[mi], bfr[ni], acc[mi][ni]);
    __syncthreads();
  }

  #pragma unroll
  for (int mi=0;mi<4;mi++){
    #pragma unroll
    for (int ni=0;ni<4;ni++){
      int col = col0 + wcol + ni*16 + (lane&15);
      float bsv = bias[col];
      #pragma unroll
      for (int r=0;r<4;r++){
        long grow = row0 + wrow + mi*16 + (lane>>4)*4 + r;
        C[grow*OUT_ + col] = acc[mi][ni][r] + bsv;
      }
    }
  }
}

extern "C" void kernel_launch(void* const* d_in, const int* in_sizes, int n_in,
                              void* d_out, int out_size, void* d_ws, size_t ws_size,
                              hipStream_t stream) {
  const float* hidden = (const float*)d_in[0];
  const float* Wp     = (const float*)d_in[1];
  const float* bp     = (const float*)d_in[2];
  const float* Wo     = (const float*)d_in[3];
  const float* bo     = (const float*)d_in[4];
  float* out    = (float*)d_out;
  float* fstate = out + (long)M_ * OUT_;

  char* w = (char*)d_ws;
  // overlay region [0,64MB): scan intermediates
  unsigned short* khT   = (unsigned short*)w;                     // 8 MB
  unsigned short* vT    = (unsigned short*)(w + 8388608);         // 8 MB
  float*          Gc    = (float*)(w + 16777216);                 // 0.5 MB
  unsigned short* Ut    = (unsigned short*)(w + 17301504);        // 32 MB (also cellT)
  unsigned short* obf   = (unsigned short*)(w + 50855936);        // 8 MB
  float*          segB  = (float*)(w + 59244544);                 // 4 MB
  float*          segG  = (float*)(w + 63438848);                 // 32 KB
  // persistent region
  unsigned short* Wot = (unsigned short*)(w + 67108864);          // 0.25 MB
  unsigned short* Wpt = (unsigned short*)(w + 67371008);          // 1 MB
  unsigned short* qbf = (unsigned short*)(w + 68419584);          // 8 MB
  unsigned short* kbf = (unsigned short*)(w + 76808192);          // 8 MB
  unsigned short* vbf = (unsigned short*)(w + 85196800);          // 8 MB
  float*          gf  = (float*)(w + 93585408);                   // 16 MB

  convT<<<dim3(NPROJ/32, H_/32), 256, 0, stream>>>(Wp, Wpt, H_, NPROJ);    // Wpt[512][1024]
  convT<<<dim3(OUT_/32, V_/32), 256, 0, stream>>>(Wo, Wot, V_, OUT_);      // Wot[1024][128]
  proj_mfma8<<<dim3(2, 256), 512, 0, stream>>>(hidden, Wpt, bp, qbf, kbf, gf, vbf);
  prep<<<dim3(NC, B_), 128, 0, stream>>>(gf, qbf, kbf, vbf, khT, vT, Gc);
  chunkstate<<<dim3(NC, B_), 256, 0, stream>>>(khT, vT, Ut);
  seqstate_a<<<dim3(16, 8, B_), 256, 0, stream>>>(Gc, Ut, segB, segG);
  seqstate_b<<<dim3(16, 8, B_), 256, 0, stream>>>(Gc, Ut, segB, segG, fstate);
  chunkout<<<dim3(NC, B_), 256, 0, stream>>>(qbf, kbf, vT, Ut, obf);
  out_mfma<<<dim3(8, 256), 256, 0, stream>>>(obf, Wot, bo, out);
}

// Round 13
// 177.865 us; speedup vs baseline: 1.6722x; 1.6722x over previous
//
#include <hip/hip_runtime.h>
#include <math.h>

#define B_ 8
#define T_ 4096
#define H_ 1024
#define K_ 128
#define V_ 128
#define OUT_ 1024
#define NPROJ 512
#define M_ (B_*T_)          // 32768
#define CC 32               // chunk length
#define NC 128              // chunks per batch

typedef __attribute__((ext_vector_type(8))) short bf16x8;
typedef __attribute__((ext_vector_type(4))) float f32x4;

__device__ inline unsigned short f2bf(float f){
  union{float f; unsigned int u;} x; x.f = f;
  unsigned int r = x.u + 0x7fff + ((x.u>>16)&1);   // RNE
  return (unsigned short)(r>>16);
}
__device__ inline float bf2f(unsigned short u){
  union{unsigned int i; float f;} x; x.i = ((unsigned int)u)<<16; return x.f;
}

#define GL16(gp, lp) __builtin_amdgcn_global_load_lds(\
  (const __attribute__((address_space(1))) unsigned int*)(gp), \
  (__attribute__((address_space(3))) unsigned int*)(lp), 16, 0, 0)

#define MFMA16(a,b,c) __builtin_amdgcn_mfma_f32_16x16x32_bf16((a),(b),(c),0,0,0)

// ---------------- merged transpose+convert for both weights
// blocks [0,512): Wpt[n][k]=bf16(Wp[k][n])  (N=512, Kd=1024) -> 16x32 tiles
// blocks [512,640): Wot[n][k]=bf16(Wo[k][n]) (N=1024, Kd=128) -> 32x4 tiles
__global__ __launch_bounds__(256)
void convT2(const float* __restrict__ Wp, const float* __restrict__ Wo,
            unsigned short* __restrict__ Wpt, unsigned short* __restrict__ Wot) {
  __shared__ float t[32][33];
  int tx = threadIdx.x & 31, ty = threadIdx.x >> 5;   // ty 0..7
  const float* src; unsigned short* dst; int Kd, N, n0, k0;
  int bid = blockIdx.x;
  if (bid < 512) { src = Wp; dst = Wpt; Kd = 1024; N = 512;
    n0 = (bid & 15)*32; k0 = (bid >> 4)*32; }
  else { int j = bid - 512; src = Wo; dst = Wot; Kd = 128; N = 1024;
    n0 = (j & 31)*32; k0 = (j >> 5)*32; }
  #pragma unroll
  for (int r=0;r<4;r++){
    int k = ty*4 + r;
    t[k][tx] = src[(long)(k0+k)*N + n0 + tx];
  }
  __syncthreads();
  #pragma unroll
  for (int r=0;r<4;r++){
    int n = ty*4 + r;
    dst[(long)(n0+n)*Kd + k0 + tx] = f2bf(t[tx][n]);
  }
}

// ---------------- proj MFMA GEMM v4 (R6 best): BM=128, BN=256, BK=64, 512 thr
// Single-buffer LDS 50KB, 2 barriers/K-step, 16 K-steps. sA pad-72; sB XOR-swizzled.
__global__ __launch_bounds__(512, 4)
void proj_mfma4(const float* __restrict__ A, const unsigned short* __restrict__ Bt,
                const float* __restrict__ bias,
                unsigned short* __restrict__ qbf, unsigned short* __restrict__ kbf,
                float* __restrict__ gf, unsigned short* __restrict__ vbf) {
  __shared__ unsigned short sA[128*72];   // 18 KB, stride 72
  __shared__ unsigned short sB[256*64];   // 32 KB, swizzled slots
  int tid = threadIdx.x, lane = tid & 63, wid = tid >> 6;
  int wm = wid >> 2, wn = wid & 3;
  int l16 = lane & 15, g8 = (lane >> 4) * 8;
  long row0 = (long)blockIdx.y * 128;
  int col0 = blockIdx.x * 256;

  int arow = tid >> 2, acol0 = (tid & 3) * 16;
  const float* Ab = A + (row0 + arow) * 1024 + acol0;
  int srowB = lane >> 3;
  int scolB = (((lane & 7) ^ (srowB & 7)) * 8);

  f32x4 acc[4][4];
  #pragma unroll
  for (int i=0;i<4;i++)
    #pragma unroll
    for (int j=0;j<4;j++) acc[i][j] = (f32x4){0.f,0.f,0.f,0.f};

  float4 ra[4];
  #define LDA(k0_) { _Pragma("unroll") \
    for (int j_=0;j_<4;j_++) ra[j_] = *(const float4*)(Ab + (k0_) + j_*4); }
  #define STA() { \
    unsigned short o_[16]; \
    _Pragma("unroll") \
    for (int j_=0;j_<4;j_++){ \
      o_[j_*4+0]=f2bf(ra[j_].x); o_[j_*4+1]=f2bf(ra[j_].y); \
      o_[j_*4+2]=f2bf(ra[j_].z); o_[j_*4+3]=f2bf(ra[j_].w); \
    } \
    *(uint4*)&sA[arow*72 + acol0]     = ((uint4*)o_)[0]; \
    *(uint4*)&sA[arow*72 + acol0 + 8] = ((uint4*)o_)[1]; \
  }
  #define STB(k0_) { _Pragma("unroll") \
    for (int i_=0;i_<4;i_++){ \
      int r_ = wid*32 + i_*8; \
      GL16(Bt + (long)(col0 + r_ + srowB)*1024 + (k0_) + scolB, &sB[r_*64]); \
    } }

  LDA(0);
  for (int t = 0; t < 16; ++t) {
    STA();
    STB(t*64);
    __syncthreads();                 // sA written (lgkm), sB landed (vmcnt)
    if (t < 15) { LDA(t*64 + 64); }  // prefetch next A under compute
    #pragma unroll
    for (int kk2 = 0; kk2 < 2; ++kk2) {
      int kk = kk2 * 32;
      bf16x8 af[4], bf[4];
      #pragma unroll
      for (int mi=0;mi<4;mi++)
        af[mi] = *(const bf16x8*)&sA[(wm*64 + mi*16 + l16)*72 + kk + g8];
      #pragma unroll
      for (int ni=0;ni<4;ni++){
        int brow = wn*64 + ni*16 + l16;
        int slot = ((kk + g8) >> 3) ^ (brow & 7);
        bf[ni] = *(const bf16x8*)&sB[brow*64 + slot*8];
      }
      #pragma unroll
      for (int mi=0;mi<4;mi++)
        #pragma unroll
        for (int ni=0;ni<4;ni++)
          acc[mi][ni] = MFMA16(af[mi], bf[ni], acc[mi][ni]);
    }
    __syncthreads();                 // compute done; also drains A prefetch
  }
  #undef LDA
  #undef STA
  #undef STB

  // epilogue: wave's 64-col strip -> segment seg of {q,k,g,v}
  int seg = blockIdx.x*2 + (wn>>1);          // 0..3, wave-uniform
  int cbase = (wn&1)*64;
  #pragma unroll
  for (int mi=0;mi<4;mi++){
    #pragma unroll
    for (int ni=0;ni<4;ni++){
      int c = cbase + ni*16 + l16;           // 0..127 within segment
      float bsv = bias[seg*128 + c];
      #pragma unroll
      for (int r=0;r<4;r++){
        long grow = row0 + wm*64 + mi*16 + (lane>>4)*4 + r;
        float v = acc[mi][ni][r] + bsv;
        long off = grow*128 + c;
        if (seg == 0)      qbf[off] = f2bf(v);
        else if (seg == 1) kbf[off] = f2bf(1.f/(1.f+__expf(-v)));
        else if (seg == 2) gf[off]  = 1.f/(1.f+__expf(-v));
        else               vbf[off] = f2bf(v);
      }
    }
  }
}

// ---------------- prep_cs: fused prep + chunkstate. grid (NC, B_), 256 thr.
// Phase 1 (2 threads/k, 16 t each): cumprod, q~/k~ in-place, k^/v into LDS, vT, Gc.
// Phase 2: chunkstate MFMA from LDS -> Ut.
__global__ __launch_bounds__(256)
void prep_cs(const float* __restrict__ gf, unsigned short* __restrict__ qbf,
             unsigned short* __restrict__ kbf, const unsigned short* __restrict__ vbf,
             unsigned short* __restrict__ vT, float* __restrict__ Gc,
             unsigned short* __restrict__ Ut) {
  __shared__ unsigned short kS[128][36];
  __shared__ unsigned short vS[128][36];
  __shared__ float gtot[2][128];
  int tid = threadIdx.x;
  int c = blockIdx.x, b = blockIdx.y;
  int k = tid & 127, half = tid >> 7;
  long base = ((long)b*T_ + (long)c*CC + half*16) * 128;

  // local inclusive prefix over 16 steps
  float gloc[16];
  {
    float G = 1.f;
    #pragma unroll
    for (int t=0;t<16;++t){
      G *= gf[base + (long)t*128 + k];
      gloc[t] = G;
    }
    gtot[half][k] = G;
  }
  __syncthreads();
  float pre  = half ? gtot[0][k] : 1.f;
  float Gtot = gtot[0][k] * gtot[1][k];

  unsigned short kh[16], vv[16];
  #pragma unroll
  for (int t=0;t<16;++t){
    long off = base + (long)t*128 + k;
    float Gt = pre * gloc[t];
    float q = bf2f(qbf[off]);
    qbf[off] = f2bf(q*Gt);
    float kk = bf2f(kbf[off]);
    float ktl = kk/Gt;
    kbf[off] = f2bf(ktl);
    kh[t] = f2bf(ktl*Gtot);
    vv[t] = vbf[off];                // lane index doubles as v index
  }
  *(uint4*)&kS[k][half*16]   = ((uint4*)kh)[0];
  *(uint4*)&kS[k][half*16+8] = ((uint4*)kh)[1];
  *(uint4*)&vS[k][half*16]   = ((uint4*)vv)[0];
  *(uint4*)&vS[k][half*16+8] = ((uint4*)vv)[1];
  long cb = (long)b*NC + c;
  if (half == 0) Gc[cb*128 + k] = Gtot;
  long tb = (cb*128 + k)*CC + half*16;
  *(uint4*)(vT + tb)     = ((uint4*)vv)[0];
  *(uint4*)(vT + tb + 8) = ((uint4*)vv)[1];
  __syncthreads();

  // chunkstate MFMA: Ut[c][v][kcol] = sum_s V[s][v] * k^[s][kcol]
  int lane = tid & 63, w = tid >> 6;
  int l16 = lane & 15, g8 = (lane >> 4) * 8;
  bf16x8 af[2], bfr[8];
  #pragma unroll
  for (int i=0;i<2;i++) af[i] = *(const bf16x8*)&vS[w*32 + i*16 + l16][g8];
  #pragma unroll
  for (int j=0;j<8;j++) bfr[j] = *(const bf16x8*)&kS[j*16 + l16][g8];
  #pragma unroll
  for (int i=0;i<2;i++){
    #pragma unroll
    for (int j=0;j<8;j++){
      f32x4 acc = (f32x4){0.f,0.f,0.f,0.f};
      acc = MFMA16(af[i], bfr[j], acc);
      int kcol = j*16 + l16;
      #pragma unroll
      for (int r=0;r<4;r++){
        int vrow = w*32 + i*16 + (lane>>4)*4 + r;
        Ut[cb*16384 + vrow*128 + kcol] = f2bf(acc[r]);
      }
    }
  }
}

// ---------------- seqstate two-level scan
// Pass A: per (b, seg of 16 chunks): local state from 0 + per-k G-product.
__global__ __launch_bounds__(256)
void seqstate_a(const float* __restrict__ Gc, const unsigned short* __restrict__ Ut,
                float* __restrict__ segB, float* __restrict__ segG) {
  int idx = blockIdx.x*256 + threadIdx.x;    // 0..4095
  int s = blockIdx.y, b = blockIdx.z;
  int v = idx>>5, k0 = (idx&31)*4;
  float cell[4] = {0.f,0.f,0.f,0.f};
  float gp[4] = {1.f,1.f,1.f,1.f};
  long ub = (long)b*NC*16384 + (long)v*128 + k0;
  long gb = (long)b*NC*128 + k0;
  int c0 = s*16;
  #pragma unroll 4
  for (int c=c0; c<c0+16; ++c){
    uint2 u = *(const uint2*)(Ut + ub + (long)c*16384);
    float4 gc = *(const float4*)(Gc + gb + (long)c*128);
    cell[0] = fmaf(cell[0], gc.x, bf2f((unsigned short)(u.x & 0xffff)));
    cell[1] = fmaf(cell[1], gc.y, bf2f((unsigned short)(u.x >> 16)));
    cell[2] = fmaf(cell[2], gc.z, bf2f((unsigned short)(u.y & 0xffff)));
    cell[3] = fmaf(cell[3], gc.w, bf2f((unsigned short)(u.y >> 16)));
    gp[0] *= gc.x; gp[1] *= gc.y; gp[2] *= gc.z; gp[3] *= gc.w;
  }
  long sb = ((long)b*8 + s)*16384 + (long)v*128 + k0;
  *(float4*)(segB + sb) = make_float4(cell[0],cell[1],cell[2],cell[3]);
  if (v == 0)
    *(float4*)(segG + ((long)b*8 + s)*128 + k0) = make_float4(gp[0],gp[1],gp[2],gp[3]);
}

// Pass B: fold upstream segments -> incoming; re-walk own segment writing cellT.
__global__ __launch_bounds__(256)
void seqstate_b(const float* __restrict__ Gc, unsigned short* __restrict__ Ut,
                const float* __restrict__ segB, const float* __restrict__ segG,
                float* __restrict__ fstate) {
  int idx = blockIdx.x*256 + threadIdx.x;    // 0..4095
  int s = blockIdx.y, b = blockIdx.z;
  int v = idx>>5, k0 = (idx&31)*4;
  float cell[4] = {0.f,0.f,0.f,0.f};
  for (int sp=0; sp<s; ++sp){                 // uniform bound per block
    float4 bg = *(const float4*)(segG + ((long)b*8 + sp)*128 + k0);
    float4 bb = *(const float4*)(segB + ((long)b*8 + sp)*16384 + (long)v*128 + k0);
    cell[0] = fmaf(cell[0], bg.x, bb.x);
    cell[1] = fmaf(cell[1], bg.y, bb.y);
    cell[2] = fmaf(cell[2], bg.z, bb.z);
    cell[3] = fmaf(cell[3], bg.w, bb.w);
  }
  long ub = (long)b*NC*16384 + (long)v*128 + k0;
  long gb = (long)b*NC*128 + k0;
  int c0 = s*16;
  #pragma unroll 4
  for (int c=c0; c<c0+16; ++c){
    uint2 u = *(const uint2*)(Ut + ub + (long)c*16384);
    float4 gc = *(const float4*)(Gc + gb + (long)c*128);
    unsigned short cb4[4] = {f2bf(cell[0]), f2bf(cell[1]), f2bf(cell[2]), f2bf(cell[3])};
    *(uint2*)(Ut + ub + (long)c*16384) = *(uint2*)cb4;   // cellT[c] (pre-update)
    cell[0] = fmaf(cell[0], gc.x, bf2f((unsigned short)(u.x & 0xffff)));
    cell[1] = fmaf(cell[1], gc.y, bf2f((unsigned short)(u.x >> 16)));
    cell[2] = fmaf(cell[2], gc.z, bf2f((unsigned short)(u.y & 0xffff)));
    cell[3] = fmaf(cell[3], gc.w, bf2f((unsigned short)(u.y >> 16)));
  }
  if (s == 7){
    #pragma unroll
    for (int j=0;j<4;j++)
      fstate[((long)b*128 + k0 + j)*128 + v] = cell[j];
  }
}

// ---------------- chunkout_out: O = tril(Q~K~^T)@V + Q~@cellT^T, then
// out = O @ W_out + b_out written directly (fused, no obf round-trip).
#define CP 140
__global__ __launch_bounds__(256)
void chunkout_out(const unsigned short* __restrict__ qbf, const unsigned short* __restrict__ kbf,
                  const unsigned short* __restrict__ vT, const unsigned short* __restrict__ cellT,
                  const unsigned short* __restrict__ Wot, const float* __restrict__ bo,
                  float* __restrict__ out) {
  __shared__ unsigned short qS[32][CP];
  __shared__ unsigned short kS[32][CP];
  __shared__ unsigned short cS[128][CP];
  __shared__ unsigned short vS[128][36];
  __shared__ unsigned short pS[4][32][36];     // 9216 B; reused as oS[32][144]
  unsigned short (*oS)[144] = (unsigned short (*)[144])&pS[0][0][0];
  int tid = threadIdx.x, lane = tid&63, w = tid>>6;
  long cb = (long)blockIdx.y*NC + blockIdx.x;
  const unsigned short* qg = qbf + cb*4096;
  const unsigned short* kg = kbf + cb*4096;
  const unsigned short* vg = vT  + cb*4096;
  const unsigned short* cg = cellT + cb*16384;
  // stage q,k (32x128), v (128x32), cell (128x128)
  #pragma unroll
  for (int j=0;j<2;j++){
    int idx = tid + j*256;           // 512
    int r = idx>>4, c8 = (idx&15)*8;
    *(uint4*)&qS[r][c8] = *(const uint4*)(qg + r*128 + c8);
    *(uint4*)&kS[r][c8] = *(const uint4*)(kg + r*128 + c8);
    int rv = idx>>2, s8 = (idx&3)*8;
    *(uint4*)&vS[rv][s8] = *(const uint4*)(vg + rv*32 + s8);
  }
  #pragma unroll
  for (int j=0;j<8;j++){
    int idx = tid + j*256;           // 2048
    int r = idx>>4, c8 = (idx&15)*8;
    *(uint4*)&cS[r][c8] = *(const uint4*)(cg + r*128 + c8);
  }
  __syncthreads();

  int l16 = lane&15, g = lane>>4, g8 = g*8;
  // S tiles: S2[s][t], compute (s0,t0),(s0,t1),(s1,t1)
  f32x4 s00 = (f32x4){0.f,0.f,0.f,0.f}, s01 = s00, s11 = s00;
  #pragma unroll
  for (int ks=0; ks<4; ++ks){
    bf16x8 ka = *(const bf16x8*)&kS[l16][ks*32+g8];
    bf16x8 kb = *(const bf16x8*)&kS[16+l16][ks*32+g8];
    bf16x8 qa = *(const bf16x8*)&qS[l16][ks*32+g8];
    bf16x8 qb = *(const bf16x8*)&qS[16+l16][ks*32+g8];
    s00 = MFMA16(ka, qa, s00);
    s01 = MFMA16(ka, qb, s01);
    s11 = MFMA16(kb, qb, s11);
  }
  // P[t][s] = masked S2, bf16. zero quadrant t<16, s>=16
  pS[w][l16][16 + 4*g + 0] = 0; pS[w][l16][16 + 4*g + 1] = 0;
  pS[w][l16][16 + 4*g + 2] = 0; pS[w][l16][16 + 4*g + 3] = 0;
  #pragma unroll
  for (int r=0;r<4;r++){
    int sl = 4*g + r;
    pS[w][l16][sl]       = (l16 >= sl) ? f2bf(s00[r]) : (unsigned short)0;
    pS[w][16+l16][sl]    = f2bf(s01[r]);
    pS[w][16+l16][16+sl] = (l16 >= sl) ? f2bf(s11[r]) : (unsigned short)0;
  }
  // O = P@V + Q~@cellT
  f32x4 o[2][2];
  #pragma unroll
  for (int i=0;i<2;i++)
    #pragma unroll
    for (int j=0;j<2;j++) o[i][j] = (f32x4){0.f,0.f,0.f,0.f};
  {
    bf16x8 p0 = *(const bf16x8*)&pS[w][l16][g8];
    bf16x8 p1 = *(const bf16x8*)&pS[w][16+l16][g8];
    bf16x8 v0 = *(const bf16x8*)&vS[w*32 + l16][g8];
    bf16x8 v1 = *(const bf16x8*)&vS[w*32 + 16 + l16][g8];
    o[0][0] = MFMA16(p0, v0, o[0][0]);
    o[0][1] = MFMA16(p0, v1, o[0][1]);
    o[1][0] = MFMA16(p1, v0, o[1][0]);
    o[1][1] = MFMA16(p1, v1, o[1][1]);
  }
  #pragma unroll
  for (int ks=0; ks<4; ++ks){
    bf16x8 qa = *(const bf16x8*)&qS[l16][ks*32+g8];
    bf16x8 qb = *(const bf16x8*)&qS[16+l16][ks*32+g8];
    bf16x8 c0 = *(const bf16x8*)&cS[w*32 + l16][ks*32+g8];
    bf16x8 c1 = *(const bf16x8*)&cS[w*32 + 16 + l16][ks*32+g8];
    o[0][0] = MFMA16(qa, c0, o[0][0]);
    o[0][1] = MFMA16(qa, c1, o[0][1]);
    o[1][0] = MFMA16(qb, c0, o[1][0]);
    o[1][1] = MFMA16(qb, c1, o[1][1]);
  }
  __syncthreads();                   // all waves done reading pS
  // write o -> oS[t][v] (bf16), overlaying pS
  #pragma unroll
  for (int ti=0;ti<2;ti++)
    #pragma unroll
    for (int vi=0;vi<2;vi++)
      #pragma unroll
      for (int r=0;r<4;r++)
        oS[ti*16 + 4*g + r][w*32 + vi*16 + l16] = f2bf(o[ti][vi][r]);
  __syncthreads();

  // out phase: out[32 rows][1024] = oS(32x128) @ Wot^T(128x1024) + bo
  // wave w owns cols w*256..+255, in 2 halves of 128 (8 n-tiles each).
  long rowb = (long)blockIdx.y*T_ + (long)blockIdx.x*CC;
  #pragma unroll
  for (int nh=0; nh<2; ++nh){
    f32x4 oc[2][8];
    #pragma unroll
    for (int mt=0;mt<2;mt++)
      #pragma unroll
      for (int nt=0;nt<8;nt++) oc[mt][nt] = (f32x4){0.f,0.f,0.f,0.f};
    #pragma unroll
    for (int ks=0; ks<4; ++ks){
      bf16x8 a0 = *(const bf16x8*)&oS[l16][ks*32+g8];
      bf16x8 a1 = *(const bf16x8*)&oS[16+l16][ks*32+g8];
      #pragma unroll
      for (int nt=0; nt<8; ++nt){
        int n = w*256 + nh*128 + nt*16 + l16;
        bf16x8 bw = *(const bf16x8*)(Wot + (long)n*128 + ks*32 + g8);
        oc[0][nt] = MFMA16(a0, bw, oc[0][nt]);
        oc[1][nt] = MFMA16(a1, bw, oc[1][nt]);
      }
    }
    #pragma unroll
    for (int mt=0; mt<2; ++mt)
      #pragma unroll
      for (int nt=0; nt<8; ++nt){
        int col = w*256 + nh*128 + nt*16 + l16;
        float bv = bo[col];
        #pragma unroll
        for (int r=0;r<4;r++){
          long row = rowb + mt*16 + g*4 + r;
          out[row*OUT_ + col] = oc[mt][nt][r] + bv;
        }
      }
  }
}

extern "C" void kernel_launch(void* const* d_in, const int* in_sizes, int n_in,
                              void* d_out, int out_size, void* d_ws, size_t ws_size,
                              hipStream_t stream) {
  const float* hidden = (const float*)d_in[0];
  const float* Wp     = (const float*)d_in[1];
  const float* bp     = (const float*)d_in[2];
  const float* Wo     = (const float*)d_in[3];
  const float* bo     = (const float*)d_in[4];
  float* out    = (float*)d_out;
  float* fstate = out + (long)M_ * OUT_;

  char* w = (char*)d_ws;
  unsigned short* vT    = (unsigned short*)w;                     // 8 MB
  float*          Gc    = (float*)(w + 8388608);                  // 0.5 MB
  unsigned short* Ut    = (unsigned short*)(w + 8912896);         // 32 MB (also cellT)
  float*          segB  = (float*)(w + 42467328);                 // 4 MB
  float*          segG  = (float*)(w + 46661632);                 // 32 KB
  // persistent region
  unsigned short* Wot = (unsigned short*)(w + 67108864);          // 0.25 MB
  unsigned short* Wpt = (unsigned short*)(w + 67371008);          // 1 MB
  unsigned short* qbf = (unsigned short*)(w + 68419584);          // 8 MB
  unsigned short* kbf = (unsigned short*)(w + 76808192);          // 8 MB
  unsigned short* vbf = (unsigned short*)(w + 85196800);          // 8 MB
  float*          gf  = (float*)(w + 93585408);                   // 16 MB

  convT2<<<640, 256, 0, stream>>>(Wp, Wo, Wpt, Wot);
  proj_mfma4<<<dim3(2, 256), 512, 0, stream>>>(hidden, Wpt, bp, qbf, kbf, gf, vbf);
  prep_cs<<<dim3(NC, B_), 256, 0, stream>>>(gf, qbf, kbf, vbf, vT, Gc, Ut);
  seqstate_a<<<dim3(16, 8, B_), 256, 0, stream>>>(Gc, Ut, segB, segG);
  seqstate_b<<<dim3(16, 8, B_), 256, 0, stream>>>(Gc, Ut, segB, segG, fstate);
  chunkout_out<<<dim3(NC, B_), 256, 0, stream>>>(qbf, kbf, vT, Ut, Wot, bo, out);
}

// Round 14
// 156.531 us; speedup vs baseline: 1.9001x; 1.1363x over previous
//
#include <hip/hip_runtime.h>
#include <math.h>

#define B_ 8
#define T_ 4096
#define H_ 1024
#define K_ 128
#define V_ 128
#define OUT_ 1024
#define NPROJ 512
#define M_ (B_*T_)          // 32768
#define CC 32               // chunk length
#define NC 128              // chunks per batch

typedef __attribute__((ext_vector_type(8))) short bf16x8;
typedef __attribute__((ext_vector_type(4))) float f32x4;

__device__ inline unsigned short f2bf(float f){
  union{float f; unsigned int u;} x; x.f = f;
  unsigned int r = x.u + 0x7fff + ((x.u>>16)&1);   // RNE
  return (unsigned short)(r>>16);
}
__device__ inline float bf2f(unsigned short u){
  union{unsigned int i; float f;} x; x.i = ((unsigned int)u)<<16; return x.f;
}

#define GL16(gp, lp) __builtin_amdgcn_global_load_lds(\
  (const __attribute__((address_space(1))) unsigned int*)(gp), \
  (__attribute__((address_space(3))) unsigned int*)(lp), 16, 0, 0)

#define MFMA16(a,b,c) __builtin_amdgcn_mfma_f32_16x16x32_bf16((a),(b),(c),0,0,0)

// ---------------- merged transpose+convert for both weights
__global__ __launch_bounds__(256)
void convT2(const float* __restrict__ Wp, const float* __restrict__ Wo,
            unsigned short* __restrict__ Wpt, unsigned short* __restrict__ Wot) {
  __shared__ float t[32][33];
  int tx = threadIdx.x & 31, ty = threadIdx.x >> 5;   // ty 0..7
  const float* src; unsigned short* dst; int Kd, N, n0, k0;
  int bid = blockIdx.x;
  if (bid < 512) { src = Wp; dst = Wpt; Kd = 1024; N = 512;
    n0 = (bid & 15)*32; k0 = (bid >> 4)*32; }
  else { int j = bid - 512; src = Wo; dst = Wot; Kd = 128; N = 1024;
    n0 = (j & 31)*32; k0 = (j >> 5)*32; }
  #pragma unroll
  for (int r=0;r<4;r++){
    int k = ty*4 + r;
    t[k][tx] = src[(long)(k0+k)*N + n0 + tx];
  }
  __syncthreads();
  #pragma unroll
  for (int r=0;r<4;r++){
    int n = ty*4 + r;
    dst[(long)(n0+n)*Kd + k0 + tx] = f2bf(t[tx][n]);
  }
}

// ---------------- proj MFMA GEMM v4 + T1 XCD-pairing
// BM=128, BN=256, BK=64, 512 thr. Grid 512 (1-D, remapped so (bx=0,y),(bx=1,y)
// land on the SAME XCD ids 8 apart => partner's A panel is L2-hot).
__global__ __launch_bounds__(512, 4)
void proj_mfma4(const float* __restrict__ A, const unsigned short* __restrict__ Bt,
                const float* __restrict__ bias,
                unsigned short* __restrict__ qbf, unsigned short* __restrict__ kbf,
                float* __restrict__ gf, unsigned short* __restrict__ vbf) {
  __shared__ unsigned short sA[128*72];   // 18 KB, stride 72
  __shared__ unsigned short sB[256*64];   // 32 KB, swizzled slots
  int tid = threadIdx.x, lane = tid & 63, wid = tid >> 6;
  int wm = wid >> 2, wn = wid & 3;
  int l16 = lane & 15, g8 = (lane >> 4) * 8;
  int id = blockIdx.x;
  int bx = (id >> 3) & 1;                 // j & 1
  int by = (id & 7)*32 + (id >> 4);       // xcd*32 + (j>>1), bijective
  long row0 = (long)by * 128;
  int col0 = bx * 256;

  int arow = tid >> 2, acol0 = (tid & 3) * 16;
  const float* Ab = A + (row0 + arow) * 1024 + acol0;
  int srowB = lane >> 3;
  int scolB = (((lane & 7) ^ (srowB & 7)) * 8);

  f32x4 acc[4][4];
  #pragma unroll
  for (int i=0;i<4;i++)
    #pragma unroll
    for (int j=0;j<4;j++) acc[i][j] = (f32x4){0.f,0.f,0.f,0.f};

  float4 ra[4];
  #define LDA(k0_) { _Pragma("unroll") \
    for (int j_=0;j_<4;j_++) ra[j_] = *(const float4*)(Ab + (k0_) + j_*4); }
  #define STA() { \
    unsigned short o_[16]; \
    _Pragma("unroll") \
    for (int j_=0;j_<4;j_++){ \
      o_[j_*4+0]=f2bf(ra[j_].x); o_[j_*4+1]=f2bf(ra[j_].y); \
      o_[j_*4+2]=f2bf(ra[j_].z); o_[j_*4+3]=f2bf(ra[j_].w); \
    } \
    *(uint4*)&sA[arow*72 + acol0]     = ((uint4*)o_)[0]; \
    *(uint4*)&sA[arow*72 + acol0 + 8] = ((uint4*)o_)[1]; \
  }
  #define STB(k0_) { _Pragma("unroll") \
    for (int i_=0;i_<4;i_++){ \
      int r_ = wid*32 + i_*8; \
      GL16(Bt + (long)(col0 + r_ + srowB)*1024 + (k0_) + scolB, &sB[r_*64]); \
    } }

  LDA(0);
  for (int t = 0; t < 16; ++t) {
    STA();
    STB(t*64);
    __syncthreads();                 // sA written (lgkm), sB landed (vmcnt)
    if (t < 15) { LDA(t*64 + 64); }  // prefetch next A under compute
    #pragma unroll
    for (int kk2 = 0; kk2 < 2; ++kk2) {
      int kk = kk2 * 32;
      bf16x8 af[4], bf[4];
      #pragma unroll
      for (int mi=0;mi<4;mi++)
        af[mi] = *(const bf16x8*)&sA[(wm*64 + mi*16 + l16)*72 + kk + g8];
      #pragma unroll
      for (int ni=0;ni<4;ni++){
        int brow = wn*64 + ni*16 + l16;
        int slot = ((kk + g8) >> 3) ^ (brow & 7);
        bf[ni] = *(const bf16x8*)&sB[brow*64 + slot*8];
      }
      #pragma unroll
      for (int mi=0;mi<4;mi++)
        #pragma unroll
        for (int ni=0;ni<4;ni++)
          acc[mi][ni] = MFMA16(af[mi], bf[ni], acc[mi][ni]);
    }
    __syncthreads();                 // compute done; also drains A prefetch
  }
  #undef LDA
  #undef STA
  #undef STB

  // epilogue: wave's 64-col strip -> segment seg of {q,k,g,v}
  int seg = bx*2 + (wn>>1);                  // 0..3, wave-uniform
  int cbase = (wn&1)*64;
  #pragma unroll
  for (int mi=0;mi<4;mi++){
    #pragma unroll
    for (int ni=0;ni<4;ni++){
      int c = cbase + ni*16 + l16;           // 0..127 within segment
      float bsv = bias[seg*128 + c];
      #pragma unroll
      for (int r=0;r<4;r++){
        long grow = row0 + wm*64 + mi*16 + (lane>>4)*4 + r;
        float v = acc[mi][ni][r] + bsv;
        long off = grow*128 + c;
        if (seg == 0)      qbf[off] = f2bf(v);
        else if (seg == 1) kbf[off] = f2bf(1.f/(1.f+__expf(-v)));
        else if (seg == 2) gf[off]  = 1.f/(1.f+__expf(-v));
        else               vbf[off] = f2bf(v);
      }
    }
  }
}

// ---------------- prep_cs: fused prep + chunkstate. grid (NC, B_), 256 thr.
__global__ __launch_bounds__(256)
void prep_cs(const float* __restrict__ gf, unsigned short* __restrict__ qbf,
             unsigned short* __restrict__ kbf, const unsigned short* __restrict__ vbf,
             unsigned short* __restrict__ vT, float* __restrict__ Gc,
             unsigned short* __restrict__ Ut) {
  __shared__ unsigned short kS[128][36];
  __shared__ unsigned short vS[128][36];
  __shared__ float gtot[2][128];
  int tid = threadIdx.x;
  int c = blockIdx.x, b = blockIdx.y;
  int k = tid & 127, half = tid >> 7;
  long base = ((long)b*T_ + (long)c*CC + half*16) * 128;

  float gloc[16];
  {
    float G = 1.f;
    #pragma unroll
    for (int t=0;t<16;++t){
      G *= gf[base + (long)t*128 + k];
      gloc[t] = G;
    }
    gtot[half][k] = G;
  }
  __syncthreads();
  float pre  = half ? gtot[0][k] : 1.f;
  float Gtot = gtot[0][k] * gtot[1][k];

  unsigned short kh[16], vv[16];
  #pragma unroll
  for (int t=0;t<16;++t){
    long off = base + (long)t*128 + k;
    float Gt = pre * gloc[t];
    float q = bf2f(qbf[off]);
    qbf[off] = f2bf(q*Gt);
    float kk = bf2f(kbf[off]);
    float ktl = kk/Gt;
    kbf[off] = f2bf(ktl);
    kh[t] = f2bf(ktl*Gtot);
    vv[t] = vbf[off];
  }
  *(uint4*)&kS[k][half*16]   = ((uint4*)kh)[0];
  *(uint4*)&kS[k][half*16+8] = ((uint4*)kh)[1];
  *(uint4*)&vS[k][half*16]   = ((uint4*)vv)[0];
  *(uint4*)&vS[k][half*16+8] = ((uint4*)vv)[1];
  long cb = (long)b*NC + c;
  if (half == 0) Gc[cb*128 + k] = Gtot;
  long tb = (cb*128 + k)*CC + half*16;
  *(uint4*)(vT + tb)     = ((uint4*)vv)[0];
  *(uint4*)(vT + tb + 8) = ((uint4*)vv)[1];
  __syncthreads();

  int lane = tid & 63, w = tid >> 6;
  int l16 = lane & 15, g8 = (lane >> 4) * 8;
  bf16x8 af[2], bfr[8];
  #pragma unroll
  for (int i=0;i<2;i++) af[i] = *(const bf16x8*)&vS[w*32 + i*16 + l16][g8];
  #pragma unroll
  for (int j=0;j<8;j++) bfr[j] = *(const bf16x8*)&kS[j*16 + l16][g8];
  #pragma unroll
  for (int i=0;i<2;i++){
    #pragma unroll
    for (int j=0;j<8;j++){
      f32x4 acc = (f32x4){0.f,0.f,0.f,0.f};
      acc = MFMA16(af[i], bfr[j], acc);
      int kcol = j*16 + l16;
      #pragma unroll
      for (int r=0;r<4;r++){
        int vrow = w*32 + i*16 + (lane>>4)*4 + r;
        Ut[cb*16384 + vrow*128 + kcol] = f2bf(acc[r]);
      }
    }
  }
}

// ---------------- seqstate two-level scan
__global__ __launch_bounds__(256)
void seqstate_a(const float* __restrict__ Gc, const unsigned short* __restrict__ Ut,
                float* __restrict__ segB, float* __restrict__ segG) {
  int idx = blockIdx.x*256 + threadIdx.x;    // 0..4095
  int s = blockIdx.y, b = blockIdx.z;
  int v = idx>>5, k0 = (idx&31)*4;
  float cell[4] = {0.f,0.f,0.f,0.f};
  float gp[4] = {1.f,1.f,1.f,1.f};
  long ub = (long)b*NC*16384 + (long)v*128 + k0;
  long gb = (long)b*NC*128 + k0;
  int c0 = s*16;
  #pragma unroll 4
  for (int c=c0; c<c0+16; ++c){
    uint2 u = *(const uint2*)(Ut + ub + (long)c*16384);
    float4 gc = *(const float4*)(Gc + gb + (long)c*128);
    cell[0] = fmaf(cell[0], gc.x, bf2f((unsigned short)(u.x & 0xffff)));
    cell[1] = fmaf(cell[1], gc.y, bf2f((unsigned short)(u.x >> 16)));
    cell[2] = fmaf(cell[2], gc.z, bf2f((unsigned short)(u.y & 0xffff)));
    cell[3] = fmaf(cell[3], gc.w, bf2f((unsigned short)(u.y >> 16)));
    gp[0] *= gc.x; gp[1] *= gc.y; gp[2] *= gc.z; gp[3] *= gc.w;
  }
  long sb = ((long)b*8 + s)*16384 + (long)v*128 + k0;
  *(float4*)(segB + sb) = make_float4(cell[0],cell[1],cell[2],cell[3]);
  if (v == 0)
    *(float4*)(segG + ((long)b*8 + s)*128 + k0) = make_float4(gp[0],gp[1],gp[2],gp[3]);
}

__global__ __launch_bounds__(256)
void seqstate_b(const float* __restrict__ Gc, unsigned short* __restrict__ Ut,
                const float* __restrict__ segB, const float* __restrict__ segG,
                float* __restrict__ fstate) {
  int idx = blockIdx.x*256 + threadIdx.x;    // 0..4095
  int s = blockIdx.y, b = blockIdx.z;
  int v = idx>>5, k0 = (idx&31)*4;
  float cell[4] = {0.f,0.f,0.f,0.f};
  for (int sp=0; sp<s; ++sp){
    float4 bg = *(const float4*)(segG + ((long)b*8 + sp)*128 + k0);
    float4 bb = *(const float4*)(segB + ((long)b*8 + sp)*16384 + (long)v*128 + k0);
    cell[0] = fmaf(cell[0], bg.x, bb.x);
    cell[1] = fmaf(cell[1], bg.y, bb.y);
    cell[2] = fmaf(cell[2], bg.z, bb.z);
    cell[3] = fmaf(cell[3], bg.w, bb.w);
  }
  long ub = (long)b*NC*16384 + (long)v*128 + k0;
  long gb = (long)b*NC*128 + k0;
  int c0 = s*16;
  #pragma unroll 4
  for (int c=c0; c<c0+16; ++c){
    uint2 u = *(const uint2*)(Ut + ub + (long)c*16384);
    float4 gc = *(const float4*)(Gc + gb + (long)c*128);
    unsigned short cb4[4] = {f2bf(cell[0]), f2bf(cell[1]), f2bf(cell[2]), f2bf(cell[3])};
    *(uint2*)(Ut + ub + (long)c*16384) = *(uint2*)cb4;   // cellT[c] (pre-update)
    cell[0] = fmaf(cell[0], gc.x, bf2f((unsigned short)(u.x & 0xffff)));
    cell[1] = fmaf(cell[1], gc.y, bf2f((unsigned short)(u.x >> 16)));
    cell[2] = fmaf(cell[2], gc.z, bf2f((unsigned short)(u.y & 0xffff)));
    cell[3] = fmaf(cell[3], gc.w, bf2f((unsigned short)(u.y >> 16)));
  }
  if (s == 7){
    #pragma unroll
    for (int j=0;j<4;j++)
      fstate[((long)b*128 + k0 + j)*128 + v] = cell[j];
  }
}

// ---------------- chunkout_out v2: GL16 staging (linear LDS + XOR-swizzled
// source + swizzled reads, rule 21), NT out stores.
// LDS: qS/kS 32x128, cS 128x128, vS 128x32 (all linear), pS padded.
__global__ __launch_bounds__(256)
void chunkout_out(const unsigned short* __restrict__ qbf, const unsigned short* __restrict__ kbf,
                  const unsigned short* __restrict__ vT, const unsigned short* __restrict__ cellT,
                  const unsigned short* __restrict__ Wot, const float* __restrict__ bo,
                  float* __restrict__ out) {
  __shared__ __align__(16) unsigned short qS[32*128];
  __shared__ __align__(16) unsigned short kS[32*128];
  __shared__ __align__(16) unsigned short cS[128*128];
  __shared__ __align__(16) unsigned short vS[128*32];
  __shared__ __align__(16) unsigned short pS[4][32][36];   // 9216 B; reused as oS[32][144]
  unsigned short (*oS)[144] = (unsigned short (*)[144])&pS[0][0][0];
  int tid = threadIdx.x, lane = tid&63, w = tid>>6;
  long cb = (long)blockIdx.y*NC + blockIdx.x;
  const unsigned short* qg = qbf + cb*4096;
  const unsigned short* kg = kbf + cb*4096;
  const unsigned short* vg = vT  + cb*4096;
  const unsigned short* cg = cellT + cb*16384;

  // frag index helpers (swizzled-on-read, matching pre-swizzled GL16 source)
  #define IDX128(row_, kks_, g8_) ((row_)*128 + (((((kks_)*4) + ((g8_)>>3)) ^ ((row_)&7))*8))
  #define IDXV(row_, g8_)   ((row_)*32 + (((((g8_)>>3)) ^ (((row_)>>1)&3))*8))

  // GL16 staging: dest linear (wave-uniform base + lane*16), source pre-swizzled
  {
    // qS, kS: 32 rows x 256B. wave w: rows w*8..w*8+7 (2 instrs x 4 rows)
    #pragma unroll
    for (int i=0;i<2;i++){
      int r0 = w*8 + i*4;
      int row = r0 + (lane>>4), sl = lane&15;
      long soff = (long)row*128 + ((sl ^ (row&7))*8);
      GL16(qg + soff, &qS[r0*128]);
      GL16(kg + soff, &kS[r0*128]);
    }
    // cS: 128 rows x 256B. wave w: rows w*32..+31 (8 instrs x 4 rows)
    #pragma unroll
    for (int i=0;i<8;i++){
      int r0 = w*32 + i*4;
      int row = r0 + (lane>>4), sl = lane&15;
      GL16(cg + (long)row*128 + ((sl ^ (row&7))*8), &cS[r0*128]);
    }
    // vS: 128 rows x 64B. wave w: rows w*32..+31 (2 instrs x 16 rows)
    #pragma unroll
    for (int i=0;i<2;i++){
      int r0 = w*32 + i*16;
      int row = r0 + (lane>>2), sl = lane&3;
      GL16(vg + (long)row*32 + ((sl ^ ((row>>1)&3))*8), &vS[r0*32]);
    }
  }
  __syncthreads();

  int l16 = lane&15, g = lane>>4, g8 = g*8;
  // S tiles: S2[s][t], compute (s0,t0),(s0,t1),(s1,t1)
  f32x4 s00 = (f32x4){0.f,0.f,0.f,0.f}, s01 = s00, s11 = s00;
  #pragma unroll
  for (int ks=0; ks<4; ++ks){
    bf16x8 ka = *(const bf16x8*)&kS[IDX128(l16, ks, g8)];
    bf16x8 kb = *(const bf16x8*)&kS[IDX128(16+l16, ks, g8)];
    bf16x8 qa = *(const bf16x8*)&qS[IDX128(l16, ks, g8)];
    bf16x8 qb = *(const bf16x8*)&qS[IDX128(16+l16, ks, g8)];
    s00 = MFMA16(ka, qa, s00);
    s01 = MFMA16(ka, qb, s01);
    s11 = MFMA16(kb, qb, s11);
  }
  // P[t][s] = masked S2, bf16. zero quadrant t<16, s>=16
  pS[w][l16][16 + 4*g + 0] = 0; pS[w][l16][16 + 4*g + 1] = 0;
  pS[w][l16][16 + 4*g + 2] = 0; pS[w][l16][16 + 4*g + 3] = 0;
  #pragma unroll
  for (int r=0;r<4;r++){
    int sl = 4*g + r;
    pS[w][l16][sl]       = (l16 >= sl) ? f2bf(s00[r]) : (unsigned short)0;
    pS[w][16+l16][sl]    = f2bf(s01[r]);
    pS[w][16+l16][16+sl] = (l16 >= sl) ? f2bf(s11[r]) : (unsigned short)0;
  }
  // O = P@V + Q~@cellT
  f32x4 o[2][2];
  #pragma unroll
  for (int i=0;i<2;i++)
    #pragma unroll
    for (int j=0;j<2;j++) o[i][j] = (f32x4){0.f,0.f,0.f,0.f};
  {
    bf16x8 p0 = *(const bf16x8*)&pS[w][l16][g8];
    bf16x8 p1 = *(const bf16x8*)&pS[w][16+l16][g8];
    bf16x8 v0 = *(const bf16x8*)&vS[IDXV(w*32 + l16, g8)];
    bf16x8 v1 = *(const bf16x8*)&vS[IDXV(w*32 + 16 + l16, g8)];
    o[0][0] = MFMA16(p0, v0, o[0][0]);
    o[0][1] = MFMA16(p0, v1, o[0][1]);
    o[1][0] = MFMA16(p1, v0, o[1][0]);
    o[1][1] = MFMA16(p1, v1, o[1][1]);
  }
  #pragma unroll
  for (int ks=0; ks<4; ++ks){
    bf16x8 qa = *(const bf16x8*)&qS[IDX128(l16, ks, g8)];
    bf16x8 qb = *(const bf16x8*)&qS[IDX128(16+l16, ks, g8)];
    bf16x8 c0 = *(const bf16x8*)&cS[IDX128(w*32 + l16, ks, g8)];
    bf16x8 c1 = *(const bf16x8*)&cS[IDX128(w*32 + 16 + l16, ks, g8)];
    o[0][0] = MFMA16(qa, c0, o[0][0]);
    o[0][1] = MFMA16(qa, c1, o[0][1]);
    o[1][0] = MFMA16(qb, c0, o[1][0]);
    o[1][1] = MFMA16(qb, c1, o[1][1]);
  }
  __syncthreads();                   // all waves done reading pS
  #pragma unroll
  for (int ti=0;ti<2;ti++)
    #pragma unroll
    for (int vi=0;vi<2;vi++)
      #pragma unroll
      for (int r=0;r<4;r++)
        oS[ti*16 + 4*g + r][w*32 + vi*16 + l16] = f2bf(o[ti][vi][r]);
  __syncthreads();

  // out phase: out[32 rows][1024] = oS(32x128) @ Wot^T(128x1024) + bo
  long rowb = (long)blockIdx.y*T_ + (long)blockIdx.x*CC;
  #pragma unroll
  for (int nh=0; nh<2; ++nh){
    f32x4 oc[2][8];
    #pragma unroll
    for (int mt=0;mt<2;mt++)
      #pragma unroll
      for (int nt=0;nt<8;nt++) oc[mt][nt] = (f32x4){0.f,0.f,0.f,0.f};
    #pragma unroll
    for (int ks=0; ks<4; ++ks){
      bf16x8 a0 = *(const bf16x8*)&oS[l16][ks*32+g8];
      bf16x8 a1 = *(const bf16x8*)&oS[16+l16][ks*32+g8];
      #pragma unroll
      for (int nt=0; nt<8; ++nt){
        int n = w*256 + nh*128 + nt*16 + l16;
        bf16x8 bw = *(const bf16x8*)(Wot + (long)n*128 + ks*32 + g8);
        oc[0][nt] = MFMA16(a0, bw, oc[0][nt]);
        oc[1][nt] = MFMA16(a1, bw, oc[1][nt]);
      }
    }
    #pragma unroll
    for (int mt=0; mt<2; ++mt)
      #pragma unroll
      for (int nt=0; nt<8; ++nt){
        int col = w*256 + nh*128 + nt*16 + l16;
        float bv = bo[col];
        #pragma unroll
        for (int r=0;r<4;r++){
          long row = rowb + mt*16 + g*4 + r;
          __builtin_nontemporal_store(oc[mt][nt][r] + bv, &out[row*OUT_ + col]);
        }
      }
  }
  #undef IDX128
  #undef IDXV
}

extern "C" void kernel_launch(void* const* d_in, const int* in_sizes, int n_in,
                              void* d_out, int out_size, void* d_ws, size_t ws_size,
                              hipStream_t stream) {
  const float* hidden = (const float*)d_in[0];
  const float* Wp     = (const float*)d_in[1];
  const float* bp     = (const float*)d_in[2];
  const float* Wo     = (const float*)d_in[3];
  const float* bo     = (const float*)d_in[4];
  float* out    = (float*)d_out;
  float* fstate = out + (long)M_ * OUT_;

  char* w = (char*)d_ws;
  unsigned short* vT    = (unsigned short*)w;                     // 8 MB
  float*          Gc    = (float*)(w + 8388608);                  // 0.5 MB
  unsigned short* Ut    = (unsigned short*)(w + 8912896);         // 32 MB (also cellT)
  float*          segB  = (float*)(w + 42467328);                 // 4 MB
  float*          segG  = (float*)(w + 46661632);                 // 32 KB
  // persistent region
  unsigned short* Wot = (unsigned short*)(w + 67108864);          // 0.25 MB
  unsigned short* Wpt = (unsigned short*)(w + 67371008);          // 1 MB
  unsigned short* qbf = (unsigned short*)(w + 68419584);          // 8 MB
  unsigned short* kbf = (unsigned short*)(w + 76808192);          // 8 MB
  unsigned short* vbf = (unsigned short*)(w + 85196800);          // 8 MB
  float*          gf  = (float*)(w + 93585408);                   // 16 MB

  convT2<<<640, 256, 0, stream>>>(Wp, Wo, Wpt, Wot);
  proj_mfma4<<<512, 512, 0, stream>>>(hidden, Wpt, bp, qbf, kbf, gf, vbf);
  prep_cs<<<dim3(NC, B_), 256, 0, stream>>>(gf, qbf, kbf, vbf, vT, Gc, Ut);
  seqstate_a<<<dim3(16, 8, B_), 256, 0, stream>>>(Gc, Ut, segB, segG);
  seqstate_b<<<dim3(16, 8, B_), 256, 0, stream>>>(Gc, Ut, segB, segG, fstate);
  chunkout_out<<<dim3(NC, B_), 256, 0, stream>>>(qbf, kbf, vT, Ut, Wot, bo, out);
}